// Round 6
// baseline (178.966 us; speedup 1.0000x reference)
//
#include <hip/hip_runtime.h>
#include <hip/hip_bf16.h>

typedef unsigned short u16;
typedef unsigned int u32;
typedef __attribute__((ext_vector_type(8))) short bf16x8;   // 8 bf16 (4 VGPRs)
typedef __attribute__((ext_vector_type(4))) short s16x4;
typedef __attribute__((ext_vector_type(4))) float f32x4;

#define NN 4096

__device__ __forceinline__ u16 f2bf(float f) {
    union { float f; u32 u; } v; v.f = f;
    u32 r = v.u + 0x7fffu + ((v.u >> 16) & 1u);   // RNE (inputs finite)
    return (u16)(r >> 16);
}

// ---------------- K1: deg = rowsum(A); inv_d = 1/(deg+1) ----------------
__global__ void rowsum_kernel(const float* __restrict__ A, float* __restrict__ invd) {
    const int row = blockIdx.x;
    const float4* a4 = reinterpret_cast<const float4*>(A + (size_t)row * NN);
    float s = 0.f;
    #pragma unroll
    for (int i = 0; i < 4; ++i) {
        float4 v = a4[threadIdx.x + i * 256];
        s += v.x + v.y + v.z + v.w;
    }
    #pragma unroll
    for (int off = 32; off > 0; off >>= 1) s += __shfl_down(s, off, 64);
    __shared__ float ws[4];
    if ((threadIdx.x & 63) == 0) ws[threadIdx.x >> 6] = s;
    __syncthreads();
    if (threadIdx.x == 0) {
        float t = ws[0] + ws[1] + ws[2] + ws[3];
        invd[row] = 1.0f / (t + 1.0f);
    }
}

// ------- K2: temp = 0.5*h + 0.5*(A + I)*inv_d[col]  -> bf16 [M][K] -------
__global__ void make_temp_kernel(const float* __restrict__ A, const float* __restrict__ h,
                                 const float* __restrict__ invd, u16* __restrict__ T) {
    const size_t g = ((size_t)blockIdx.x * 256 + threadIdx.x) * 8;
    const int row = (int)(g >> 12);
    const int col = (int)(g & 4095);
    const float4* a4 = reinterpret_cast<const float4*>(A + g);
    const float4* h4 = reinterpret_cast<const float4*>(h + g);
    const float4* d4 = reinterpret_cast<const float4*>(invd + col);
    float4 a0 = a4[0], a1 = a4[1];
    float4 h0 = h4[0], h1 = h4[1];
    float4 dd0 = d4[0], dd1 = d4[1];
    float av[8] = {a0.x,a0.y,a0.z,a0.w,a1.x,a1.y,a1.z,a1.w};
    float hv[8] = {h0.x,h0.y,h0.z,h0.w,h1.x,h1.y,h1.z,h1.w};
    float dv[8] = {dd0.x,dd0.y,dd0.z,dd0.w,dd1.x,dd1.y,dd1.z,dd1.w};
    bf16x8 o;
    #pragma unroll
    for (int j = 0; j < 8; ++j) {
        float aa = av[j] + ((col + j == row) ? 1.0f : 0.0f);
        float t = 0.5f * hv[j] + 0.5f * aa * dv[j];
        o[j] = (short)f2bf(t);
    }
    *reinterpret_cast<bf16x8*>(T + g) = o;
}

// --------- K3: Wt[n][k] = bf16(W[k][n])  (LDS 64x64 tile transpose) ---------
__global__ void transposeW_kernel(const float* __restrict__ W, u16* __restrict__ Wt) {
    __shared__ float tile[64][65];
    const int nt = blockIdx.x & 63;
    const int kt = blockIdx.x >> 6;
    const int k0 = kt * 64, n0 = nt * 64;
    const int tr = threadIdx.x >> 4;          // 0..15
    const int tc = (threadIdx.x & 15) * 4;    // 0..60
    #pragma unroll
    for (int rr = 0; rr < 64; rr += 16) {
        float4 v = *reinterpret_cast<const float4*>(&W[(size_t)(k0 + tr + rr) * NN + n0 + tc]);
        tile[tr + rr][tc + 0] = v.x;
        tile[tr + rr][tc + 1] = v.y;
        tile[tr + rr][tc + 2] = v.z;
        tile[tr + rr][tc + 3] = v.w;
    }
    __syncthreads();
    #pragma unroll
    for (int rr = 0; rr < 64; rr += 16) {
        const int n = tr + rr;
        s16x4 o;
        #pragma unroll
        for (int j = 0; j < 4; ++j) o[j] = (short)f2bf(tile[tc + j][n]);
        *reinterpret_cast<s16x4*>(&Wt[(size_t)(n0 + n) * NN + k0 + tc]) = o;
    }
}

// ============ K4: C[M][N] = temp[M][K] @ Wt[N][K]^T (bf16 MFMA) ============
// R6: 256x256 tile, BK=32, TRI-buffered LDS (96KB), stage-2-ahead with
// counted vmcnt(4), full fragment prefetch: MFMAs of step t consume regs
// read during t-1 (zero lgkm dependency), ds_reads of step t fill t+1.
// DS pipe and MFMA pipe overlap instead of serializing (R5 was serial).

#define GLD16(g, l) __builtin_amdgcn_global_load_lds( \
    (const __attribute__((address_space(1))) void*)(g), \
    (__attribute__((address_space(3))) void*)(l), 16, 0, 0)

__global__ __launch_bounds__(512, 2) void gemm_kernel(
    const u16* __restrict__ Atl,   // [M][K] bf16 (temp)
    const u16* __restrict__ Btl,   // [N][K] bf16 (Wt)
    float* __restrict__ C)         // [M][N] f32
{
    __shared__ u16 SA[3][8192];    // [buf][256 rows x 32 k]
    __shared__ u16 SB[3][8192];

    const int tid  = threadIdx.x;
    const int wid  = tid >> 6;     // 0..7
    const int lane = tid & 63;
    const int llo  = lane & 15;
    const int lhi  = lane >> 4;    // 0..3
    const int wr   = wid >> 2;     // 0..1  (M half: 128 rows)
    const int wc   = wid & 3;      // 0..3  (N quarter: 64 cols)

    // XCD swizzle (grid=256, 256%8==0 -> bijective)
    const int swz = ((int)blockIdx.x & 7) * 32 + ((int)blockIdx.x >> 3);
    const int bm = swz >> 4, bn = swz & 15;
    const int tileRow = bm * 256, tileCol = bn * 256;

    // ---- staging (R2-proven): linear LDS dest, inverse-swizzled source ----
    const int r0 = tid >> 2;                                 // 0..127
    const int kc = (((tid & 3) ^ ((r0 >> 1) & 3)) << 3);
    const size_t R128 = (size_t)128 * NN;
    const u16* gA = Atl + (size_t)(tileRow + r0) * NN + kc;
    const u16* gB = Btl + (size_t)(tileCol + r0) * NN + kc;

    #define STAGE(WB, KOFF) do { \
        GLD16(gA + (KOFF),        &SA[WB][tid * 8]); \
        GLD16(gA + R128 + (KOFF), &SA[WB][4096 + tid * 8]); \
        GLD16(gB + (KOFF),        &SB[WB][tid * 8]); \
        GLD16(gB + R128 + (KOFF), &SB[WB][4096 + tid * 8]); } while (0)

    // ---- swizzled read offsets (R2-proven, 0 conflicts) ----
    int offA[8], offB[4];
    #pragma unroll
    for (int m = 0; m < 8; ++m) {
        const int row = wr * 128 + m * 16 + llo;
        offA[m] = row * 32 + ((lhi ^ ((row >> 1) & 3)) << 3);
    }
    #pragma unroll
    for (int n = 0; n < 4; ++n) {
        const int row = wc * 64 + n * 16 + llo;
        offB[n] = row * 32 + ((lhi ^ ((row >> 1) & 3)) << 3);
    }

    f32x4 acc[8][4];
    #pragma unroll
    for (int m = 0; m < 8; ++m)
        #pragma unroll
        for (int n = 0; n < 4; ++n)
            acc[m][n] = (f32x4){0.f, 0.f, 0.f, 0.f};

    bf16x8 aE[8], bE[4], aO[8], bO[4];   // ping-pong frag sets (static idx only)

    // ---- prologue: stage tiles 0,1; read frags(0) into E set ----
    STAGE(0, 0);
    STAGE(1, 32);
    asm volatile("s_waitcnt vmcnt(4)" ::: "memory");   // stage(0) done
    __builtin_amdgcn_s_barrier();
    asm volatile("" ::: "memory");
    #pragma unroll
    for (int m = 0; m < 8; ++m) aE[m] = *reinterpret_cast<const bf16x8*>(&SA[0][0] + offA[m]);
    #pragma unroll
    for (int n = 0; n < 4; ++n) bE[n] = *reinterpret_cast<const bf16x8*>(&SB[0][0] + offB[n]);

    int wb = 2;        // stage dest buf for tile t+2 (t=0)
    int rb = 1;        // read buf for frags(t+1) (t=0)
    int koff = 64;     // element k-offset of tile t+2 (t=0)

    // STEP(t): SG = stage tile t+2, RD = read frags(t+1) into (AN,BN),
    //          VM0 = use vmcnt(0) instead of vmcnt(4), AC/BC consumed.
    #define STEP(SG, VM0, RD, AC, BC, AN, BN) do { \
        if (SG) { STAGE(wb, koff); koff += 32; } \
        if (VM0) asm volatile("s_waitcnt vmcnt(0)" ::: "memory"); \
        else     asm volatile("s_waitcnt vmcnt(4)" ::: "memory"); \
        __builtin_amdgcn_s_barrier(); \
        asm volatile("" ::: "memory"); \
        const u16* rA = &SA[rb][0]; \
        const u16* rB = &SB[rb][0]; \
        if (RD) { \
            _Pragma("unroll") \
            for (int m = 0; m < 4; ++m) AN[m] = *reinterpret_cast<const bf16x8*>(rA + offA[m]); \
        } \
        __builtin_amdgcn_sched_barrier(0); \
        __builtin_amdgcn_s_setprio(1); \
        _Pragma("unroll") \
        for (int m = 0; m < 4; ++m) \
            _Pragma("unroll") \
            for (int n = 0; n < 4; ++n) \
                acc[m][n] = __builtin_amdgcn_mfma_f32_16x16x32_bf16(AC[m], BC[n], acc[m][n], 0, 0, 0); \
        __builtin_amdgcn_s_setprio(0); \
        __builtin_amdgcn_sched_barrier(0); \
        if (RD) { \
            _Pragma("unroll") \
            for (int m = 4; m < 8; ++m) AN[m] = *reinterpret_cast<const bf16x8*>(rA + offA[m]); \
            _Pragma("unroll") \
            for (int n = 0; n < 4; ++n) BN[n] = *reinterpret_cast<const bf16x8*>(rB + offB[n]); \
        } \
        __builtin_amdgcn_sched_barrier(0); \
        __builtin_amdgcn_s_setprio(1); \
        _Pragma("unroll") \
        for (int m = 4; m < 8; ++m) \
            _Pragma("unroll") \
            for (int n = 0; n < 4; ++n) \
                acc[m][n] = __builtin_amdgcn_mfma_f32_16x16x32_bf16(AC[m], BC[n], acc[m][n], 0, 0, 0); \
        __builtin_amdgcn_s_setprio(0); \
        rb = (rb == 2) ? 0 : rb + 1; \
        wb = (wb == 2) ? 0 : wb + 1; \
    } while (0)

    #pragma unroll 1
    for (int tt = 0; tt < 64; ++tt) {
        const bool sg = tt < 63;
        // t = 2tt: consume E, fill O.  vmcnt(0) only at t=126 (tt=63).
        STEP(sg, !sg, true, aE, bE, aO, bO);
        // t = 2tt+1: consume O, fill E. last step (t=127): no stage/read.
        STEP(sg, !sg && false, sg, aO, bO, aE, bE);
    }
    #undef STEP
    #undef STAGE

    // ---- epilogue: C/D layout col=lane&15, row=(lane>>4)*4+reg ----
    #pragma unroll
    for (int m = 0; m < 8; ++m) {
        #pragma unroll
        for (int n = 0; n < 4; ++n) {
            const size_t rbase = (size_t)(tileRow + wr * 128 + m * 16 + lhi * 4) * NN
                               + tileCol + wc * 64 + n * 16 + llo;
            #pragma unroll
            for (int j = 0; j < 4; ++j)
                C[rbase + (size_t)j * NN] = acc[m][n][j];
        }
    }
}

// ---------------------------------------------------------------------------
extern "C" void kernel_launch(void* const* d_in, const int* in_sizes, int n_in,
                              void* d_out, int out_size, void* d_ws, size_t ws_size,
                              hipStream_t stream) {
    const float* A = (const float*)d_in[0];
    const float* h = (const float*)d_in[1];
    const float* W = (const float*)d_in[2];
    float* out = (float*)d_out;

    // workspace layout: inv_d (16KB) | temp bf16 (32MB) | Wt bf16 (32MB)
    float* invd = (float*)d_ws;
    u16* temp = (u16*)((char*)d_ws + 16384);
    u16* wt   = temp + (size_t)NN * NN;

    rowsum_kernel<<<NN, 256, 0, stream>>>(A, invd);
    make_temp_kernel<<<(NN * (size_t)NN) / (256 * 8), 256, 0, stream>>>(A, h, invd, temp);
    transposeW_kernel<<<(NN / 64) * (NN / 64), 256, 0, stream>>>(W, wt);
    gemm_kernel<<<256, 512, 0, stream>>>(temp, wt, out);
}

// Round 7
// 178.546 us; speedup vs baseline: 1.0024x; 1.0024x over previous
//
#include <hip/hip_runtime.h>
#include <hip/hip_bf16.h>

typedef unsigned short u16;
typedef unsigned int u32;
typedef __attribute__((ext_vector_type(8))) short bf16x8;   // 8 bf16 (4 VGPRs)
typedef __attribute__((ext_vector_type(4))) short s16x4;
typedef __attribute__((ext_vector_type(4))) float f32x4;

#define NN 4096

__device__ __forceinline__ u16 f2bf(float f) {
    union { float f; u32 u; } v; v.f = f;
    u32 r = v.u + 0x7fffu + ((v.u >> 16) & 1u);   // RNE (inputs finite)
    return (u16)(r >> 16);
}

// ---------------- K1: deg = rowsum(A); inv_d = 1/(deg+1) ----------------
__global__ void rowsum_kernel(const float* __restrict__ A, float* __restrict__ invd) {
    const int row = blockIdx.x;
    const float4* a4 = reinterpret_cast<const float4*>(A + (size_t)row * NN);
    float s = 0.f;
    #pragma unroll
    for (int i = 0; i < 4; ++i) {
        float4 v = a4[threadIdx.x + i * 256];
        s += v.x + v.y + v.z + v.w;
    }
    #pragma unroll
    for (int off = 32; off > 0; off >>= 1) s += __shfl_down(s, off, 64);
    __shared__ float ws[4];
    if ((threadIdx.x & 63) == 0) ws[threadIdx.x >> 6] = s;
    __syncthreads();
    if (threadIdx.x == 0) {
        float t = ws[0] + ws[1] + ws[2] + ws[3];
        invd[row] = 1.0f / (t + 1.0f);
    }
}

// ------- K2: temp = 0.5*h + 0.5*(A + I)*inv_d[col]  -> bf16 [M][K] -------
__global__ void make_temp_kernel(const float* __restrict__ A, const float* __restrict__ h,
                                 const float* __restrict__ invd, u16* __restrict__ T) {
    const size_t g = ((size_t)blockIdx.x * 256 + threadIdx.x) * 8;
    const int row = (int)(g >> 12);
    const int col = (int)(g & 4095);
    const float4* a4 = reinterpret_cast<const float4*>(A + g);
    const float4* h4 = reinterpret_cast<const float4*>(h + g);
    const float4* d4 = reinterpret_cast<const float4*>(invd + col);
    float4 a0 = a4[0], a1 = a4[1];
    float4 h0 = h4[0], h1 = h4[1];
    float4 dd0 = d4[0], dd1 = d4[1];
    float av[8] = {a0.x,a0.y,a0.z,a0.w,a1.x,a1.y,a1.z,a1.w};
    float hv[8] = {h0.x,h0.y,h0.z,h0.w,h1.x,h1.y,h1.z,h1.w};
    float dv[8] = {dd0.x,dd0.y,dd0.z,dd0.w,dd1.x,dd1.y,dd1.z,dd1.w};
    bf16x8 o;
    #pragma unroll
    for (int j = 0; j < 8; ++j) {
        float aa = av[j] + ((col + j == row) ? 1.0f : 0.0f);
        float t = 0.5f * hv[j] + 0.5f * aa * dv[j];
        o[j] = (short)f2bf(t);
    }
    *reinterpret_cast<bf16x8*>(T + g) = o;
}

// --------- K3: Wt[n][k] = bf16(W[k][n])  (LDS 64x64 tile transpose) ---------
__global__ void transposeW_kernel(const float* __restrict__ W, u16* __restrict__ Wt) {
    __shared__ float tile[64][65];
    const int nt = blockIdx.x & 63;
    const int kt = blockIdx.x >> 6;
    const int k0 = kt * 64, n0 = nt * 64;
    const int tr = threadIdx.x >> 4;          // 0..15
    const int tc = (threadIdx.x & 15) * 4;    // 0..60
    #pragma unroll
    for (int rr = 0; rr < 64; rr += 16) {
        float4 v = *reinterpret_cast<const float4*>(&W[(size_t)(k0 + tr + rr) * NN + n0 + tc]);
        tile[tr + rr][tc + 0] = v.x;
        tile[tr + rr][tc + 1] = v.y;
        tile[tr + rr][tc + 2] = v.z;
        tile[tr + rr][tc + 3] = v.w;
    }
    __syncthreads();
    #pragma unroll
    for (int rr = 0; rr < 64; rr += 16) {
        const int n = tr + rr;
        s16x4 o;
        #pragma unroll
        for (int j = 0; j < 4; ++j) o[j] = (short)f2bf(tile[tc + j][n]);
        *reinterpret_cast<s16x4*>(&Wt[(size_t)(n0 + n) * NN + k0 + tc]) = o;
    }
}

// ============ K4: C = temp[M][K] @ Wt[N][K]^T — 8-phase m201-style ============
// 256x256 tile, BK=64, 2 bufs (128KB), phases read 12/4/8/0 + one C-quadrant
// (16 MFMA) each, per-phase {reads|stage -> barrier -> lgkmcnt(0) -> MFMA ->
// barrier}. Stages: B(g+2)@P3(g), A(g+2)@P4(g) (earliest WAR-safe slots);
// vmcnt(8) once per tile at P4 -> forced-landing distance >= 4 phases.

#define GLD16(g, l) __builtin_amdgcn_global_load_lds( \
    (const __attribute__((address_space(1))) void*)(g), \
    (__attribute__((address_space(3))) void*)(l), 16, 0, 0)

#define SBAR()  do { __builtin_amdgcn_sched_barrier(0); \
    __builtin_amdgcn_s_barrier(); asm volatile("" ::: "memory"); } while (0)
#define LGKM0() do { asm volatile("s_waitcnt lgkmcnt(0)" ::: "memory"); \
    __builtin_amdgcn_sched_barrier(0); } while (0)

__global__ __launch_bounds__(512, 2) void gemm_kernel(
    const u16* __restrict__ Atl,   // [M][K] bf16 (temp)
    const u16* __restrict__ Btl,   // [N][K] bf16 (Wt)
    float* __restrict__ C)         // [M][N] f32
{
    __shared__ u16 S[2][4][8192];  // [buf][Alo|Ahi|Blo|Bhi][128 rows x 64 k]

    const int tid  = threadIdx.x;
    const int wid  = tid >> 6;     // 0..7
    const int lane = tid & 63;
    const int llo  = lane & 15;
    const int lhi  = lane >> 4;    // 0..3
    const int wr   = wid >> 2;     // 0..1  (M half -> reads only A-half wr)
    const int wc   = wid & 3;      // 0..3  (N quarter -> B-half wc>>1)

    // XCD swizzle (grid=256, 256%8==0 -> bijective)
    const int swz = ((int)blockIdx.x & 7) * 32 + ((int)blockIdx.x >> 3);
    const int bm = swz >> 4, bn = swz & 15;
    const int tileRow = bm * 256, tileCol = bn * 256;

    // ---- staging: linear LDS dest, inverse-swizzled source (R5-proven) ----
    const int r0 = tid >> 3;                                // 0..63
    const int kc = (((tid & 7) ^ (r0 & 7)) << 3);
    const size_t R64  = (size_t)64 * NN;
    const size_t R128 = (size_t)128 * NN;
    const u16* gA = Atl + (size_t)(tileRow + r0) * NN + kc;
    const u16* gB = Btl + (size_t)(tileCol + r0) * NN + kc;

    #define STG(PTR, DSTBASE) do { \
        GLD16((PTR),       (DSTBASE) + tid * 8); \
        GLD16((PTR) + R64, (DSTBASE) + 4096 + tid * 8); } while (0)

    // ---- swizzled read offsets (region-relative; ks1 = off^32) ----
    int offA[8], offB[4];
    #pragma unroll
    for (int m = 0; m < 8; ++m) {
        const int row = m * 16 + llo;
        offA[m] = row * 64 + ((lhi ^ (row & 7)) << 3);
    }
    #pragma unroll
    for (int n = 0; n < 4; ++n) {
        const int row = (wc & 1) * 64 + n * 16 + llo;
        offB[n] = row * 64 + ((lhi ^ (row & 7)) << 3);
    }

    f32x4 acc[8][4];
    #pragma unroll
    for (int m = 0; m < 8; ++m)
        #pragma unroll
        for (int n = 0; n < 4; ++n)
            acc[m][n] = (f32x4){0.f, 0.f, 0.f, 0.f};

    // ---- prologue: stage tiles 0 and 1 fully ----
    {
        u16* b0p = (u16*)&S[0][0][0];
        u16* b1p = (u16*)&S[1][0][0];
        STG(gA,              b0p + 0 * 8192);
        STG(gA + R128,       b0p + 1 * 8192);
        STG(gB,              b0p + 2 * 8192);
        STG(gB + R128,       b0p + 3 * 8192);
        STG(gA + 64,         b1p + 0 * 8192);
        STG(gA + R128 + 64,  b1p + 1 * 8192);
        STG(gB + 64,         b1p + 2 * 8192);
        STG(gB + R128 + 64,  b1p + 3 * 8192);
    }
    asm volatile("s_waitcnt vmcnt(8)" ::: "memory");   // tile 0 landed
    __builtin_amdgcn_s_barrier();
    asm volatile("" ::: "memory");

    #pragma unroll 1
    for (int g = 0; g < 64; ++g) {
        u16* cb = (u16*)&S[g & 1][0][0];
        const u16* sAr = cb + wr * 8192;
        const u16* sBr = cb + (2 + (wc >> 1)) * 8192;
        const int koff = (g + 2) * 64;
        const bool stg = g <= 61;

        bf16x8 a0[4][2], a1[4][2], b0[2][2], b1[2][2];

        // ===== PHASE 1: read A[0..3]+B[0..1] (12) | MFMA quad (m0-3 x n0-1) =====
        #pragma unroll
        for (int m = 0; m < 4; ++m) {
            a0[m][0] = *reinterpret_cast<const bf16x8*>(sAr + offA[m]);
            a0[m][1] = *reinterpret_cast<const bf16x8*>(sAr + (offA[m] ^ 32));
        }
        #pragma unroll
        for (int n = 0; n < 2; ++n) {
            b0[n][0] = *reinterpret_cast<const bf16x8*>(sBr + offB[n]);
            b0[n][1] = *reinterpret_cast<const bf16x8*>(sBr + (offB[n] ^ 32));
        }
        asm volatile("s_waitcnt lgkmcnt(8)" ::: "memory");   // throttle (12 reads)
        SBAR();
        LGKM0();
        __builtin_amdgcn_s_setprio(1);
        #pragma unroll
        for (int ks = 0; ks < 2; ++ks)
            #pragma unroll
            for (int m = 0; m < 4; ++m)
                #pragma unroll
                for (int n = 0; n < 2; ++n)
                    acc[m][n] = __builtin_amdgcn_mfma_f32_16x16x32_bf16(a0[m][ks], b0[n][ks], acc[m][n], 0, 0, 0);
        __builtin_amdgcn_s_setprio(0);
        SBAR();

        // ===== PHASE 2: read B[2..3] (4) | MFMA quad (m0-3 x n2-3) =====
        #pragma unroll
        for (int n = 0; n < 2; ++n) {
            b1[n][0] = *reinterpret_cast<const bf16x8*>(sBr + offB[2 + n]);
            b1[n][1] = *reinterpret_cast<const bf16x8*>(sBr + (offB[2 + n] ^ 32));
        }
        SBAR();
        LGKM0();
        __builtin_amdgcn_s_setprio(1);
        #pragma unroll
        for (int ks = 0; ks < 2; ++ks)
            #pragma unroll
            for (int m = 0; m < 4; ++m)
                #pragma unroll
                for (int n = 0; n < 2; ++n)
                    acc[m][2 + n] = __builtin_amdgcn_mfma_f32_16x16x32_bf16(a0[m][ks], b1[n][ks], acc[m][2 + n], 0, 0, 0);
        __builtin_amdgcn_s_setprio(0);
        SBAR();

        // ===== PHASE 3: read A[4..7] (8) | stage B(g+2) | MFMA (m4-7 x n0-1) =====
        // B(g) reads completed at P2's closing barrier -> WAR-safe.
        #pragma unroll
        for (int m = 0; m < 4; ++m) {
            a1[m][0] = *reinterpret_cast<const bf16x8*>(sAr + offA[4 + m]);
            a1[m][1] = *reinterpret_cast<const bf16x8*>(sAr + (offA[4 + m] ^ 32));
        }
        if (stg) {
            STG(gB + koff,        cb + 2 * 8192);
            STG(gB + R128 + koff, cb + 3 * 8192);
        }
        SBAR();
        LGKM0();
        __builtin_amdgcn_s_setprio(1);
        #pragma unroll
        for (int ks = 0; ks < 2; ++ks)
            #pragma unroll
            for (int m = 0; m < 4; ++m)
                #pragma unroll
                for (int n = 0; n < 2; ++n)
                    acc[4 + m][n] = __builtin_amdgcn_mfma_f32_16x16x32_bf16(a1[m][ks], b0[n][ks], acc[4 + m][n], 0, 0, 0);
        __builtin_amdgcn_s_setprio(0);
        SBAR();

        // ===== PHASE 4: stage A(g+2) | vmcnt | MFMA (m4-7 x n2-3) =====
        // A(g) reads completed at P3's closing barrier -> WAR-safe.
        if (stg) {
            STG(gA + koff,        cb + 0 * 8192);
            STG(gA + R128 + koff, cb + 1 * 8192);
        }
        if (g <= 61)      asm volatile("s_waitcnt vmcnt(8)" ::: "memory");  // tile g+1 landed
        else if (g == 62) asm volatile("s_waitcnt vmcnt(0)" ::: "memory");  // drain for tile 63
        SBAR();
        __builtin_amdgcn_s_setprio(1);
        #pragma unroll
        for (int ks = 0; ks < 2; ++ks)
            #pragma unroll
            for (int m = 0; m < 4; ++m)
                #pragma unroll
                for (int n = 0; n < 2; ++n)
                    acc[4 + m][2 + n] = __builtin_amdgcn_mfma_f32_16x16x32_bf16(a1[m][ks], b1[n][ks], acc[4 + m][2 + n], 0, 0, 0);
        __builtin_amdgcn_s_setprio(0);
        if (g < 63) SBAR();
    }
    #undef STG

    // ---- epilogue: C/D layout col=lane&15, row=(lane>>4)*4+reg ----
    #pragma unroll
    for (int m = 0; m < 8; ++m) {
        #pragma unroll
        for (int n = 0; n < 4; ++n) {
            const size_t rbase = (size_t)(tileRow + wr * 128 + m * 16 + lhi * 4) * NN
                               + tileCol + wc * 64 + n * 16 + llo;
            #pragma unroll
            for (int j = 0; j < 4; ++j)
                C[rbase + (size_t)j * NN] = acc[m][n][j];
        }
    }
}

// ---------------------------------------------------------------------------
extern "C" void kernel_launch(void* const* d_in, const int* in_sizes, int n_in,
                              void* d_out, int out_size, void* d_ws, size_t ws_size,
                              hipStream_t stream) {
    const float* A = (const float*)d_in[0];
    const float* h = (const float*)d_in[1];
    const float* W = (const float*)d_in[2];
    float* out = (float*)d_out;

    // workspace layout: inv_d (16KB) | temp bf16 (32MB) | Wt bf16 (32MB)
    float* invd = (float*)d_ws;
    u16* temp = (u16*)((char*)d_ws + 16384);
    u16* wt   = temp + (size_t)NN * NN;

    rowsum_kernel<<<NN, 256, 0, stream>>>(A, invd);
    make_temp_kernel<<<(NN * (size_t)NN) / (256 * 8), 256, 0, stream>>>(A, h, invd, temp);
    transposeW_kernel<<<(NN / 64) * (NN / 64), 256, 0, stream>>>(W, wt);
    gemm_kernel<<<256, 512, 0, stream>>>(temp, wt, out);
}